// Round 1
// 794.337 us; speedup vs baseline: 1.0379x; 1.0379x over previous
//
#include <hip/hip_runtime.h>
#include <math.h>

#define N_NODES 100000
#define N_EDGES 1600000
#define D_IN 512
#define C1 128   // H1*D1
#define H1 8
#define D2 64
#define SLOPE 0.2f
#define NB_SCAN 98   // ceil(100000/1024)

typedef unsigned short u16;
typedef unsigned int u32;
typedef u16 u16x4 __attribute__((ext_vector_type(4)));
typedef u16 u16x8 __attribute__((ext_vector_type(8)));
typedef short bf16x8 __attribute__((ext_vector_type(8)));
typedef float f32x4 __attribute__((ext_vector_type(4)));

__device__ __forceinline__ u16 f2bf(float f) {
    unsigned u = __builtin_bit_cast(unsigned, f);
    u += 0x7fffu + ((u >> 16) & 1u);   // RNE
    return (u16)(u >> 16);
}
__device__ __forceinline__ float bf2f(u16 v) {
    unsigned u = ((unsigned)v) << 16;
    return __builtin_bit_cast(float, u);
}
__device__ __forceinline__ float bflo(u32 u) { return __builtin_bit_cast(float, u << 16); }
__device__ __forceinline__ float bfhi(u32 u) { return __builtin_bit_cast(float, u & 0xffff0000u); }
__device__ __forceinline__ float lrelu(float e) { return e >= 0.f ? e : SLOPE * e; }

// ---------------- W1 -> bf16 (once) ----------------
__global__ void k_prep_w1(const float* __restrict__ W1, u16* __restrict__ W1b) {
    int i = blockIdx.x * blockDim.x + threadIdx.x;   // one float4 each; 16384 total
    float4 v = ((const float4*)W1)[i];
    u16x4 b; b.x = f2bf(v.x); b.y = f2bf(v.y); b.z = f2bf(v.z); b.w = f2bf(v.w);
    ((u16x4*)W1b)[i] = b;
}

// ---------------- CSR build ----------------
__global__ void k_hist(const int* __restrict__ dst, int* __restrict__ cnt) {
    int e = blockIdx.x * blockDim.x + threadIdx.x;
    if (e < N_EDGES) atomicAdd(&cnt[dst[e]], 1);
}

__global__ void k_scan_partials(const int* __restrict__ cnt, int* __restrict__ partials) {
    __shared__ int s[256];
    int t = threadIdx.x;
    int base = blockIdx.x * 1024 + t * 4;
    int sum = 0;
#pragma unroll
    for (int j = 0; j < 4; j++) { int i = base + j; if (i < N_NODES) sum += cnt[i]; }
    s[t] = sum;
    __syncthreads();
    for (int off = 128; off > 0; off >>= 1) {
        if (t < off) s[t] += s[t + off];
        __syncthreads();
    }
    if (t == 0) partials[blockIdx.x] = s[0];
}

__global__ void k_scan_offsets(const int* __restrict__ partials, int* __restrict__ offsets,
                               int* __restrict__ row_start) {
    __shared__ int s[128];
    int t = threadIdx.x;
    int v = (t < NB_SCAN) ? partials[t] : 0;
    s[t] = v;
    __syncthreads();
    for (int off = 1; off < 128; off <<= 1) {
        int x = (t >= off) ? s[t - off] : 0;
        __syncthreads();
        s[t] += x;
        __syncthreads();
    }
    if (t < NB_SCAN) offsets[t] = s[t] - v;
    if (t == NB_SCAN - 1) row_start[N_NODES] = s[t];
}

__global__ void k_scan_final(const int* __restrict__ cnt, const int* __restrict__ offsets,
                             int* __restrict__ row_start, int* __restrict__ cursor) {
    __shared__ int s[256];
    int t = threadIdx.x;
    int base = blockIdx.x * 1024 + t * 4;
    int v[4];
    int sum = 0;
#pragma unroll
    for (int j = 0; j < 4; j++) {
        int i = base + j;
        v[j] = (i < N_NODES) ? cnt[i] : 0;
        sum += v[j];
    }
    s[t] = sum;
    __syncthreads();
    for (int off = 1; off < 256; off <<= 1) {
        int x = (t >= off) ? s[t - off] : 0;
        __syncthreads();
        s[t] += x;
        __syncthreads();
    }
    int b = offsets[blockIdx.x] + s[t] - sum;
    int e = 0;
#pragma unroll
    for (int j = 0; j < 4; j++) {
        int i = base + j;
        if (i < N_NODES) { row_start[i] = b + e; cursor[i] = b + e; }
        e += v[j];
    }
}

__global__ void k_scatter(const int* __restrict__ src, const int* __restrict__ dst,
                          int* __restrict__ cursor, int* __restrict__ csr_src) {
    int e = blockIdx.x * blockDim.x + threadIdx.x;
    if (e < N_EDGES) {
        int pos = atomicAdd(&cursor[dst[e]], 1);
        csr_src[pos] = src[e];
    }
}

// ---------------- GEMM1 (bf16 MFMA) + fused feats->out0 copy + fused el1/er1 ----------
// M_tile=64 (4 waves x 16 rows), N=128 (8 col-tiles of 16), BK=32
// eler1 layout: [node][16] = {el[h=0..7], er[h=0..7]}
__global__ __launch_bounds__(256) void k_gemm1(const float* __restrict__ feats,
                                               const u16* __restrict__ W1b,
                                               const float* __restrict__ al1,
                                               const float* __restrict__ ar1,
                                               u16* __restrict__ ft1b,
                                               float* __restrict__ out0,
                                               float* __restrict__ eler1) {
    __shared__ u16 As[64 * 40];    // [row][k] stride 40
    __shared__ u16 Bs[128 * 40];   // [o][k] stride 40
    int t = threadIdx.x;
    int m0 = blockIdx.x * 64;
    int wave = t >> 6, lane = t & 63, quad = lane >> 4, mr = lane & 15;

    f32x4 acc[8];
#pragma unroll
    for (int i = 0; i < 8; i++)
#pragma unroll
        for (int j = 0; j < 4; j++) acc[i][j] = 0.f;

    for (int kt = 0; kt < D_IN; kt += 32) {
        __syncthreads();
        // stage A: 64 rows x 32 k fp32 -> bf16 (512 float4, 2/thread); also write out0
#pragma unroll
        for (int l = 0; l < 2; ++l) {
            int idx = t + l * 256;
            int row = idx >> 3, k4 = idx & 7;
            int n = m0 + row;
            float4 v = make_float4(0.f, 0.f, 0.f, 0.f);
            if (n < N_NODES) {
                v = *(const float4*)(feats + (size_t)n * D_IN + kt + k4 * 4);
                *(float4*)(out0 + (size_t)n * D_IN + kt + k4 * 4) = v;
            }
            u16x4 b; b.x = f2bf(v.x); b.y = f2bf(v.y); b.z = f2bf(v.z); b.w = f2bf(v.w);
            *(u16x4*)(As + row * 40 + k4 * 4) = b;
        }
        // stage B: 128 rows x 32 k bf16 (512 u16x8, 2/thread)
#pragma unroll
        for (int l = 0; l < 2; ++l) {
            int idx = t + l * 256;
            int o = idx >> 2, k8 = idx & 3;
            *(u16x8*)(Bs + o * 40 + k8 * 8) = *(const u16x8*)(W1b + (size_t)o * D_IN + kt + k8 * 8);
        }
        __syncthreads();
        bf16x8 a = *(const bf16x8*)(As + (wave * 16 + mr) * 40 + quad * 8);
#pragma unroll
        for (int nt = 0; nt < 8; ++nt) {
            bf16x8 b = *(const bf16x8*)(Bs + (nt * 16 + mr) * 40 + quad * 8);
            acc[nt] = __builtin_amdgcn_mfma_f32_16x16x32_bf16(a, b, acc[nt], 0, 0, 0);
        }
    }
    // epilogue: C/D layout col=lane&15 (mr), row=quad*4+reg
    // ft1b store
#pragma unroll
    for (int nt = 0; nt < 8; ++nt)
#pragma unroll
        for (int r = 0; r < 4; ++r) {
            int n = m0 + wave * 16 + quad * 4 + r;
            if (n < N_NODES) ft1b[(size_t)n * C1 + nt * 16 + mr] = f2bf(acc[nt][r]);
        }
    // fused el1/er1: head = nt, d = mr. Reduce acc[nt][r]*a?1[nt*16+mr] over the
    // 16 mr-lanes of each quad group (masks 1,2,4,8 stay inside the group).
    float al1v[8], ar1v[8];
#pragma unroll
    for (int nt = 0; nt < 8; ++nt) { al1v[nt] = al1[nt * 16 + mr]; ar1v[nt] = ar1[nt * 16 + mr]; }
#pragma unroll
    for (int r = 0; r < 4; ++r) {
        int n = m0 + wave * 16 + quad * 4 + r;
        float sel = 0.f;
#pragma unroll
        for (int nt = 0; nt < 8; ++nt) {
            float v = acc[nt][r];
            float pl = v * al1v[nt];
            float pr = v * ar1v[nt];
#pragma unroll
            for (int off = 1; off < 16; off <<= 1) {
                pl += __shfl_xor(pl, off, 64);
                pr += __shfl_xor(pr, off, 64);
            }
            sel = (mr == nt) ? pl : sel;
            sel = (mr == nt + 8) ? pr : sel;
        }
        if (n < N_NODES) eler1[(size_t)n * 16 + mr] = sel;   // 64B coalesced per quad
    }
}

// ---------------- layer0 aggregation: one wave per dst node, channel-pair lanes ---------
// Wave-cooperative CSR index load + 8-edge gather batches (16 outstanding loads).
__global__ __launch_bounds__(256) void k_agg1(const u16* __restrict__ ft1b,
                                              const float* __restrict__ eler1,
                                              const int* __restrict__ row_start,
                                              const int* __restrict__ csr_src,
                                              float* __restrict__ h1out,
                                              u32* __restrict__ h1b) {
    int lane = threadIdx.x & 63;
    int n = blockIdx.x * 4 + (threadIdx.x >> 6);
    if (n >= N_NODES) return;
    int h = lane >> 3;                  // head for channels 2*lane, 2*lane+1
    float era = eler1[(size_t)n * 16 + 8 + h];
    int beg = row_start[n], end = row_start[n + 1];
    float a0 = 0.f, a1 = 0.f, sw = 0.f;
    const u32* ftp = (const u32*)ft1b;  // row = 64 u32
    for (int base = beg; base < end; base += 64) {
        int rem = end - base;
        int sv = csr_src[base + ((lane < rem) ? lane : 0)];   // one coalesced 256B read
        int cnt = rem < 64 ? rem : 64;
        for (int j = 0; j < cnt; j += 8) {
            int s[8];
#pragma unroll
            for (int kk = 0; kk < 8; ++kk) {
                int idx = j + kk;
                int sl = (idx < cnt) ? idx : j;     // dummy slots alias slot j (cache hit)
                s[kk] = __shfl(sv, sl, 64);
            }
            float e[8];
#pragma unroll
            for (int kk = 0; kk < 8; ++kk) e[kk] = eler1[(size_t)s[kk] * 16 + h];
            u32 f[8];
#pragma unroll
            for (int kk = 0; kk < 8; ++kk) f[kk] = ftp[(size_t)s[kk] * 64 + lane];
#pragma unroll
            for (int kk = 0; kk < 8; ++kk) {
                float w = ((j + kk) < cnt) ? __expf(lrelu(e[kk] + era)) : 0.f;
                a0 = fmaf(w, bflo(f[kk]), a0);
                a1 = fmaf(w, bfhi(f[kk]), a1);
                sw += w;
            }
        }
    }
    float r0 = (sw > 0.f) ? fmaxf(a0 / sw, 0.f) : 0.f;   // relu
    float r1 = (sw > 0.f) ? fmaxf(a1 / sw, 0.f) : 0.f;
    float2 rr; rr.x = r0; rr.y = r1;
    *(float2*)(h1out + (size_t)n * C1 + 2 * lane) = rr;
    h1b[n * 64 + lane] = (u32)f2bf(r0) | ((u32)f2bf(r1) << 16);
}

// ---------------- GEMM2 (bf16 MFMA) + fused el2/er2 ----------------
// 128 nodes/block, N=64 (4 col-tiles), K=128 staged once
__global__ __launch_bounds__(256) void k_gemm2(const u16* __restrict__ h1b,
                                               const float* __restrict__ W2,
                                               const float* __restrict__ al2,
                                               const float* __restrict__ ar2,
                                               u16* __restrict__ ft2b,
                                               float* __restrict__ el2,
                                               float* __restrict__ er2) {
    __shared__ u16 As[128 * 136];
    __shared__ u16 Bs[64 * 136];
    int t = threadIdx.x;
    int n0 = blockIdx.x * 128;
    // stage A: 128 rows x 128 bf16 = 2048 x 16B chunks, 8/thread
#pragma unroll
    for (int l = 0; l < 8; ++l) {
        int idx = t + l * 256;
        int row = idx >> 4, c8 = idx & 15;
        int n = n0 + row;
        u16x8 v;
#pragma unroll
        for (int j = 0; j < 8; j++) v[j] = 0;
        if (n < N_NODES) v = *(const u16x8*)(h1b + (size_t)n * C1 + c8 * 8);
        *(u16x8*)(As + row * 136 + c8 * 8) = v;
    }
    // stage B: W2 64x128 fp32 -> bf16 (2048 float4, 8/thread)
#pragma unroll
    for (int l = 0; l < 8; ++l) {
        int idx = t + l * 256;
        int o = idx >> 5, k4 = idx & 31;
        float4 w = *(const float4*)(W2 + (size_t)o * C1 + k4 * 4);
        u16x4 b; b.x = f2bf(w.x); b.y = f2bf(w.y); b.z = f2bf(w.z); b.w = f2bf(w.w);
        *(u16x4*)(Bs + o * 136 + k4 * 4) = b;
    }
    __syncthreads();
    int wave = t >> 6, lane = t & 63, quad = lane >> 4, mr = lane & 15;
    f32x4 acc[2][4];
#pragma unroll
    for (int i = 0; i < 2; i++)
#pragma unroll
        for (int j = 0; j < 4; j++)
#pragma unroll
            for (int r = 0; r < 4; r++) acc[i][j][r] = 0.f;
#pragma unroll
    for (int kc = 0; kc < 4; ++kc) {
        bf16x8 a0 = *(const bf16x8*)(As + (wave * 32 + mr) * 136 + kc * 32 + quad * 8);
        bf16x8 a1 = *(const bf16x8*)(As + (wave * 32 + 16 + mr) * 136 + kc * 32 + quad * 8);
#pragma unroll
        for (int nt = 0; nt < 4; ++nt) {
            bf16x8 b = *(const bf16x8*)(Bs + (nt * 16 + mr) * 136 + kc * 32 + quad * 8);
            acc[0][nt] = __builtin_amdgcn_mfma_f32_16x16x32_bf16(a0, b, acc[0][nt], 0, 0, 0);
            acc[1][nt] = __builtin_amdgcn_mfma_f32_16x16x32_bf16(a1, b, acc[1][nt], 0, 0, 0);
        }
    }
#pragma unroll
    for (int mf = 0; mf < 2; ++mf)
#pragma unroll
        for (int nt = 0; nt < 4; ++nt)
#pragma unroll
            for (int r = 0; r < 4; ++r) {
                int n = n0 + wave * 32 + mf * 16 + quad * 4 + r;
                if (n < N_NODES) ft2b[(size_t)n * D2 + nt * 16 + mr] = f2bf(acc[mf][nt][r]);
            }
    // fused el2/er2: el2[n] = sum_c ft2[n][c]*al2[c]; c = nt*16+mr
    float al2v[4], ar2v[4];
#pragma unroll
    for (int nt = 0; nt < 4; ++nt) { al2v[nt] = al2[nt * 16 + mr]; ar2v[nt] = ar2[nt * 16 + mr]; }
#pragma unroll
    for (int mf = 0; mf < 2; ++mf)
#pragma unroll
        for (int r = 0; r < 4; ++r) {
            int n = n0 + wave * 32 + mf * 16 + quad * 4 + r;
            float pl = 0.f, pr = 0.f;
#pragma unroll
            for (int nt = 0; nt < 4; ++nt) {
                float v = acc[mf][nt][r];
                pl = fmaf(v, al2v[nt], pl);
                pr = fmaf(v, ar2v[nt], pr);
            }
#pragma unroll
            for (int off = 1; off < 16; off <<= 1) {
                pl += __shfl_xor(pl, off, 64);
                pr += __shfl_xor(pr, off, 64);
            }
            if (mr == 0 && n < N_NODES) { el2[n] = pl; er2[n] = pr; }
        }
}

// ---------------- layer1 aggregation: half-wave per edge, 2 ch/lane --------------------
// Wave-cooperative CSR index load + 4-edge batches per half (8 edges in flight per wave).
__global__ __launch_bounds__(256) void k_agg2(const u16* __restrict__ ft2b,
                                              const float* __restrict__ el2,
                                              const float* __restrict__ er2,
                                              const int* __restrict__ row_start,
                                              const int* __restrict__ csr_src,
                                              float* __restrict__ out2) {
    int lane = threadIdx.x & 63;
    int n = blockIdx.x * 4 + (threadIdx.x >> 6);
    if (n >= N_NODES) return;
    int half = lane >> 5;
    int c = (lane & 31) * 2;            // channel pair
    float ern = er2[n];
    int beg = row_start[n], end = row_start[n + 1];
    float a0 = 0.f, a1 = 0.f, sw = 0.f;
    const u32* ftp = (const u32*)ft2b;  // row = 32 u32
    for (int base = beg; base < end; base += 64) {
        int rem = end - base;
        int sv = csr_src[base + ((lane < rem) ? lane : 0)];
        int cnt = rem < 64 ? rem : 64;
        for (int j = 0; j < cnt; j += 8) {
            int s[4];
#pragma unroll
            for (int kk = 0; kk < 4; ++kk) {
                int idx = j + 2 * kk + half;
                int sl = (idx < cnt) ? idx : j;
                s[kk] = __shfl(sv, sl, 64);
            }
            float e[4];
#pragma unroll
            for (int kk = 0; kk < 4; ++kk) e[kk] = el2[s[kk]];
            u32 f[4];
#pragma unroll
            for (int kk = 0; kk < 4; ++kk) f[kk] = ftp[(size_t)s[kk] * 32 + (lane & 31)];
#pragma unroll
            for (int kk = 0; kk < 4; ++kk) {
                float w = ((j + 2 * kk + half) < cnt) ? __expf(lrelu(e[kk] + ern)) : 0.f;
                a0 = fmaf(w, bflo(f[kk]), a0);
                a1 = fmaf(w, bfhi(f[kk]), a1);
                sw += w;
            }
        }
    }
    a0 += __shfl_xor(a0, 32, 64);
    a1 += __shfl_xor(a1, 32, 64);
    sw += __shfl_xor(sw, 32, 64);
    if (half == 0) {
        float2 rr;
        rr.x = (sw > 0.f) ? a0 / sw : 0.f;
        rr.y = (sw > 0.f) ? a1 / sw : 0.f;
        *(float2*)(out2 + (size_t)n * D2 + c) = rr;
    }
}

extern "C" void kernel_launch(void* const* d_in, const int* in_sizes, int n_in,
                              void* d_out, int out_size, void* d_ws, size_t ws_size,
                              hipStream_t stream) {
    const float* feats = (const float*)d_in[0];
    const int* src = (const int*)d_in[1];
    const int* dst = (const int*)d_in[2];
    const float* W1 = (const float*)d_in[3];
    const float* al1 = (const float*)d_in[4];
    const float* ar1 = (const float*)d_in[5];
    const float* W2 = (const float*)d_in[6];
    const float* al2 = (const float*)d_in[7];
    const float* ar2 = (const float*)d_in[8];

    float* out0 = (float*)d_out;                       // feats copy [N,512]
    float* out1 = out0 + (size_t)N_NODES * D_IN;       // h1 [N,128]
    float* out2 = out1 + (size_t)N_NODES * C1;         // h  [N,64]

    char* ws = (char*)d_ws;
    size_t off = 0;
    auto alloc = [&](size_t bytes) -> void* {
        void* p = ws + off;
        off = (off + bytes + 255) & ~(size_t)255;
        return p;
    };
    u16* ft1b = (u16*)alloc((size_t)N_NODES * C1 * 2);
    u16* h1b = (u16*)alloc((size_t)N_NODES * C1 * 2);
    u16* ft2b = (u16*)alloc((size_t)N_NODES * D2 * 2);
    u16* W1b = (u16*)alloc((size_t)C1 * D_IN * 2);
    float* eler1 = (float*)alloc((size_t)N_NODES * 16 * 4);   // [n][16]: el[0..7], er[0..7]
    float* el2 = (float*)alloc((size_t)N_NODES * 4);
    float* er2 = (float*)alloc((size_t)N_NODES * 4);
    int* cnt = (int*)alloc((size_t)N_NODES * 4);
    int* row_start = (int*)alloc((size_t)(N_NODES + 1) * 4);
    int* cursor = (int*)alloc((size_t)N_NODES * 4);
    int* csr_src = (int*)alloc((size_t)N_EDGES * 4);
    int* partials = (int*)alloc((size_t)NB_SCAN * 4);
    int* offsets = (int*)alloc((size_t)NB_SCAN * 4);

    // CSR build (shared by both layers)
    hipMemsetAsync(cnt, 0, (size_t)N_NODES * 4, stream);
    k_hist<<<(N_EDGES + 255) / 256, 256, 0, stream>>>(dst, cnt);
    k_scan_partials<<<NB_SCAN, 256, 0, stream>>>(cnt, partials);
    k_scan_offsets<<<1, 128, 0, stream>>>(partials, offsets, row_start);
    k_scan_final<<<NB_SCAN, 256, 0, stream>>>(cnt, offsets, row_start, cursor);
    k_scatter<<<(N_EDGES + 255) / 256, 256, 0, stream>>>(src, dst, cursor, csr_src);

    // weights prep
    k_prep_w1<<<64, 256, 0, stream>>>(W1, W1b);

    // layer 0 (gemm1 also writes out0 = feats and fused el1/er1)
    k_gemm1<<<(N_NODES + 63) / 64, 256, 0, stream>>>(feats, W1b, al1, ar1, ft1b, out0, eler1);
    k_agg1<<<(N_NODES + 3) / 4, 256, 0, stream>>>(ft1b, eler1, row_start, csr_src, out1, (u32*)h1b);

    // layer 1 (gemm2 has fused el2/er2)
    k_gemm2<<<(N_NODES + 127) / 128, 256, 0, stream>>>(h1b, W2, al2, ar2, ft2b, el2, er2);
    k_agg2<<<(N_NODES + 3) / 4, 256, 0, stream>>>(ft2b, el2, er2, row_start, csr_src, out2);
}

// Round 3
// 774.878 us; speedup vs baseline: 1.0639x; 1.0251x over previous
//
#include <hip/hip_runtime.h>
#include <math.h>

#define N_NODES 100000
#define N_EDGES 1600000
#define D_IN 512
#define C1 128   // H1*D1
#define H1 8
#define D2 64
#define SLOPE 0.2f
#define NB_SCAN 98    // ceil(100000/1024)
#define G1 1563       // ceil(100000/64) gemm1 tiles
#define NB_HIST 512   // extra blocks in gemm1 dispatch doing the dst histogram

typedef unsigned short u16;
typedef unsigned int u32;
typedef u16 u16x4 __attribute__((ext_vector_type(4)));
typedef u16 u16x8 __attribute__((ext_vector_type(8)));
typedef short bf16x8 __attribute__((ext_vector_type(8)));
typedef float f32x4 __attribute__((ext_vector_type(4)));

__device__ __forceinline__ u16 f2bf(float f) {
    unsigned u = __builtin_bit_cast(unsigned, f);
    u += 0x7fffu + ((u >> 16) & 1u);   // RNE
    return (u16)(u >> 16);
}
__device__ __forceinline__ float bf2f(u16 v) {
    unsigned u = ((unsigned)v) << 16;
    return __builtin_bit_cast(float, u);
}
__device__ __forceinline__ float bflo(u32 u) { return __builtin_bit_cast(float, u << 16); }
__device__ __forceinline__ float bfhi(u32 u) { return __builtin_bit_cast(float, u & 0xffff0000u); }
__device__ __forceinline__ float lrelu(float e) { return e >= 0.f ? e : SLOPE * e; }

// ---------------- K1: GEMM1 (bf16 MFMA, reg-prefetch) + out0 copy + fused el1/er1
//                      ∥ dst histogram (blocks >= G1) ----------------
// M_tile=64 (4 waves x 16 rows), N=128 (8 col-tiles of 16), BK=32
// eler1 layout: [node][16] = {el[h=0..7], er[h=0..7]}
__global__ __launch_bounds__(256) void k_gemm1_hist(const float* __restrict__ feats,
                                                    const float* __restrict__ W1,
                                                    const float* __restrict__ al1,
                                                    const float* __restrict__ ar1,
                                                    u16* __restrict__ ft1b,
                                                    float* __restrict__ out0,
                                                    float* __restrict__ eler1,
                                                    const int* __restrict__ dst,
                                                    int* __restrict__ cnt) {
    if (blockIdx.x >= G1) {
        // histogram partition: grid-stride over edges
        for (int e = (blockIdx.x - G1) * 256 + (int)threadIdx.x; e < N_EDGES;
             e += NB_HIST * 256)
            atomicAdd(&cnt[dst[e]], 1);
        return;
    }
    __shared__ u16 As[64 * 40];    // [row][k] stride 40
    __shared__ u16 Bs[128 * 40];   // [o][k] stride 40
    int t = threadIdx.x;
    int m0 = blockIdx.x * 64;
    int wave = t >> 6, lane = t & 63, quad = lane >> 4, mr = lane & 15;

    f32x4 acc[8];
#pragma unroll
    for (int i = 0; i < 8; i++)
#pragma unroll
        for (int j = 0; j < 4; j++) acc[i][j] = 0.f;

    // prefetch registers: A = 2 float4/thread (64x32 fp32), B = 4 float4/thread (128x32 fp32)
    float4 pa[2], pb[4];
    auto LOAD = [&](int kt) {
#pragma unroll
        for (int l = 0; l < 2; ++l) {
            int idx = t + l * 256;
            int row = idx >> 3, k4 = idx & 7;
            int n = m0 + row;
            pa[l] = make_float4(0.f, 0.f, 0.f, 0.f);
            if (n < N_NODES) pa[l] = *(const float4*)(feats + (size_t)n * D_IN + kt + k4 * 4);
        }
#pragma unroll
        for (int l = 0; l < 4; ++l) {
            int idx = t + l * 256;
            int o = idx >> 3, k4 = idx & 7;
            pb[l] = *(const float4*)(W1 + (size_t)o * D_IN + kt + k4 * 4);
        }
    };
    LOAD(0);
    for (int kt = 0; kt < D_IN; kt += 32) {
        __syncthreads();   // previous tile's LDS reads done
        // write phase: regs -> LDS (convert), + out0 stores
#pragma unroll
        for (int l = 0; l < 2; ++l) {
            int idx = t + l * 256;
            int row = idx >> 3, k4 = idx & 7;
            int n = m0 + row;
            float4 v = pa[l];
            if (n < N_NODES) *(float4*)(out0 + (size_t)n * D_IN + kt + k4 * 4) = v;
            u16x4 b; b.x = f2bf(v.x); b.y = f2bf(v.y); b.z = f2bf(v.z); b.w = f2bf(v.w);
            *(u16x4*)(As + row * 40 + k4 * 4) = b;
        }
#pragma unroll
        for (int l = 0; l < 4; ++l) {
            int idx = t + l * 256;
            int o = idx >> 3, k4 = idx & 7;
            float4 w = pb[l];
            u16x4 b; b.x = f2bf(w.x); b.y = f2bf(w.y); b.z = f2bf(w.z); b.w = f2bf(w.w);
            *(u16x4*)(Bs + o * 40 + k4 * 4) = b;
        }
        __syncthreads();
        if (kt + 32 < D_IN) LOAD(kt + 32);   // issue next tile; latency hides under MFMA
        bf16x8 a = *(const bf16x8*)(As + (wave * 16 + mr) * 40 + quad * 8);
#pragma unroll
        for (int nt = 0; nt < 8; ++nt) {
            bf16x8 b = *(const bf16x8*)(Bs + (nt * 16 + mr) * 40 + quad * 8);
            acc[nt] = __builtin_amdgcn_mfma_f32_16x16x32_bf16(a, b, acc[nt], 0, 0, 0);
        }
    }
    // epilogue: C/D layout col=lane&15 (mr), row=quad*4+reg
#pragma unroll
    for (int nt = 0; nt < 8; ++nt)
#pragma unroll
        for (int r = 0; r < 4; ++r) {
            int n = m0 + wave * 16 + quad * 4 + r;
            if (n < N_NODES) ft1b[(size_t)n * C1 + nt * 16 + mr] = f2bf(acc[nt][r]);
        }
    // fused el1/er1 from f32 accumulators
    float al1v[8], ar1v[8];
#pragma unroll
    for (int nt = 0; nt < 8; ++nt) { al1v[nt] = al1[nt * 16 + mr]; ar1v[nt] = ar1[nt * 16 + mr]; }
#pragma unroll
    for (int r = 0; r < 4; ++r) {
        int n = m0 + wave * 16 + quad * 4 + r;
        float sel = 0.f;
#pragma unroll
        for (int nt = 0; nt < 8; ++nt) {
            float v = acc[nt][r];
            float pl = v * al1v[nt];
            float pr = v * ar1v[nt];
#pragma unroll
            for (int off = 1; off < 16; off <<= 1) {
                pl += __shfl_xor(pl, off, 64);
                pr += __shfl_xor(pr, off, 64);
            }
            sel = (mr == nt) ? pl : sel;
            sel = (mr == nt + 8) ? pr : sel;
        }
        if (n < N_NODES) eler1[(size_t)n * 16 + mr] = sel;
    }
}

// ---------------- CSR build (small chained kernels — graph-capture safe) ----------------
__global__ void k_scan_partials(const int* __restrict__ cnt, int* __restrict__ partials) {
    __shared__ int s[256];
    int t = threadIdx.x;
    int base = blockIdx.x * 1024 + t * 4;
    int sum = 0;
#pragma unroll
    for (int j = 0; j < 4; j++) { int i = base + j; if (i < N_NODES) sum += cnt[i]; }
    s[t] = sum;
    __syncthreads();
    for (int off = 128; off > 0; off >>= 1) {
        if (t < off) s[t] += s[t + off];
        __syncthreads();
    }
    if (t == 0) partials[blockIdx.x] = s[0];
}

__global__ void k_scan_offsets(const int* __restrict__ partials, int* __restrict__ offsets,
                               int* __restrict__ row_start) {
    __shared__ int s[128];
    int t = threadIdx.x;
    int v = (t < NB_SCAN) ? partials[t] : 0;
    s[t] = v;
    __syncthreads();
    for (int off = 1; off < 128; off <<= 1) {
        int x = (t >= off) ? s[t - off] : 0;
        __syncthreads();
        s[t] += x;
        __syncthreads();
    }
    if (t < NB_SCAN) offsets[t] = s[t] - v;
    if (t == NB_SCAN - 1) row_start[N_NODES] = s[t];
}

__global__ void k_scan_final(const int* __restrict__ cnt, const int* __restrict__ offsets,
                             int* __restrict__ row_start, int* __restrict__ cursor) {
    __shared__ int s[256];
    int t = threadIdx.x;
    int base = blockIdx.x * 1024 + t * 4;
    int v[4];
    int sum = 0;
#pragma unroll
    for (int j = 0; j < 4; j++) {
        int i = base + j;
        v[j] = (i < N_NODES) ? cnt[i] : 0;
        sum += v[j];
    }
    s[t] = sum;
    __syncthreads();
    for (int off = 1; off < 256; off <<= 1) {
        int x = (t >= off) ? s[t - off] : 0;
        __syncthreads();
        s[t] += x;
        __syncthreads();
    }
    int b = offsets[blockIdx.x] + s[t] - sum;
    int e = 0;
#pragma unroll
    for (int j = 0; j < 4; j++) {
        int i = base + j;
        if (i < N_NODES) { row_start[i] = b + e; cursor[i] = b + e; }
        e += v[j];
    }
}

__global__ void k_scatter(const int* __restrict__ src, const int* __restrict__ dst,
                          int* __restrict__ cursor, int* __restrict__ csr_src) {
    int e = blockIdx.x * blockDim.x + threadIdx.x;
    if (e < N_EDGES) {
        int pos = atomicAdd(&cursor[dst[e]], 1);
        csr_src[pos] = src[e];
    }
}

// ---------------- layer0 aggregation: one wave per dst node, 16 edges in flight --------
__global__ __launch_bounds__(256) void k_agg1(const u16* __restrict__ ft1b,
                                              const float* __restrict__ eler1,
                                              const int* __restrict__ row_start,
                                              const int* __restrict__ csr_src,
                                              float* __restrict__ h1out,
                                              u32* __restrict__ h1b) {
    int lane = threadIdx.x & 63;
    int n = blockIdx.x * 4 + (threadIdx.x >> 6);
    if (n >= N_NODES) return;
    int h = lane >> 3;                  // head for channels 2*lane, 2*lane+1
    float era = eler1[(size_t)n * 16 + 8 + h];
    int beg = row_start[n], end = row_start[n + 1];
    float a0 = 0.f, a1 = 0.f, sw = 0.f;
    const u32* ftp = (const u32*)ft1b;  // row = 64 u32
    for (int base = beg; base < end; base += 64) {
        int rem = end - base;
        int sv = csr_src[base + ((lane < rem) ? lane : 0)];   // one coalesced 256B read
        int cnt = rem < 64 ? rem : 64;
        for (int j = 0; j < cnt; j += 16) {
            int s[16];
#pragma unroll
            for (int kk = 0; kk < 16; ++kk) {
                int idx = j + kk;
                int sl = (idx < cnt) ? idx : j;     // dummy slots alias slot j (cache hit)
                s[kk] = __shfl(sv, sl, 64);
            }
            float e[16];
#pragma unroll
            for (int kk = 0; kk < 16; ++kk) e[kk] = eler1[(size_t)s[kk] * 16 + h];
            u32 f[16];
#pragma unroll
            for (int kk = 0; kk < 16; ++kk) f[kk] = ftp[(size_t)s[kk] * 64 + lane];
#pragma unroll
            for (int kk = 0; kk < 16; ++kk) {
                float w = ((j + kk) < cnt) ? __expf(lrelu(e[kk] + era)) : 0.f;
                a0 = fmaf(w, bflo(f[kk]), a0);
                a1 = fmaf(w, bfhi(f[kk]), a1);
                sw += w;
            }
        }
    }
    float r0 = (sw > 0.f) ? fmaxf(a0 / sw, 0.f) : 0.f;   // relu
    float r1 = (sw > 0.f) ? fmaxf(a1 / sw, 0.f) : 0.f;
    float2 rr; rr.x = r0; rr.y = r1;
    *(float2*)(h1out + (size_t)n * C1 + 2 * lane) = rr;
    h1b[n * 64 + lane] = (u32)f2bf(r0) | ((u32)f2bf(r1) << 16);
}

// ---------------- GEMM2 (bf16 MFMA) + fused el2/er2 ----------------
__global__ __launch_bounds__(256) void k_gemm2(const u16* __restrict__ h1b,
                                               const float* __restrict__ W2,
                                               const float* __restrict__ al2,
                                               const float* __restrict__ ar2,
                                               u16* __restrict__ ft2b,
                                               float* __restrict__ el2,
                                               float* __restrict__ er2) {
    __shared__ u16 As[128 * 136];
    __shared__ u16 Bs[64 * 136];
    int t = threadIdx.x;
    int n0 = blockIdx.x * 128;
#pragma unroll
    for (int l = 0; l < 8; ++l) {
        int idx = t + l * 256;
        int row = idx >> 4, c8 = idx & 15;
        int n = n0 + row;
        u16x8 v;
#pragma unroll
        for (int j = 0; j < 8; j++) v[j] = 0;
        if (n < N_NODES) v = *(const u16x8*)(h1b + (size_t)n * C1 + c8 * 8);
        *(u16x8*)(As + row * 136 + c8 * 8) = v;
    }
#pragma unroll
    for (int l = 0; l < 8; ++l) {
        int idx = t + l * 256;
        int o = idx >> 5, k4 = idx & 31;
        float4 w = *(const float4*)(W2 + (size_t)o * C1 + k4 * 4);
        u16x4 b; b.x = f2bf(w.x); b.y = f2bf(w.y); b.z = f2bf(w.z); b.w = f2bf(w.w);
        *(u16x4*)(Bs + o * 136 + k4 * 4) = b;
    }
    __syncthreads();
    int wave = t >> 6, lane = t & 63, quad = lane >> 4, mr = lane & 15;
    f32x4 acc[2][4];
#pragma unroll
    for (int i = 0; i < 2; i++)
#pragma unroll
        for (int j = 0; j < 4; j++)
#pragma unroll
            for (int r = 0; r < 4; r++) acc[i][j][r] = 0.f;
#pragma unroll
    for (int kc = 0; kc < 4; ++kc) {
        bf16x8 a0 = *(const bf16x8*)(As + (wave * 32 + mr) * 136 + kc * 32 + quad * 8);
        bf16x8 a1 = *(const bf16x8*)(As + (wave * 32 + 16 + mr) * 136 + kc * 32 + quad * 8);
#pragma unroll
        for (int nt = 0; nt < 4; ++nt) {
            bf16x8 b = *(const bf16x8*)(Bs + (nt * 16 + mr) * 136 + kc * 32 + quad * 8);
            acc[0][nt] = __builtin_amdgcn_mfma_f32_16x16x32_bf16(a0, b, acc[0][nt], 0, 0, 0);
            acc[1][nt] = __builtin_amdgcn_mfma_f32_16x16x32_bf16(a1, b, acc[1][nt], 0, 0, 0);
        }
    }
#pragma unroll
    for (int mf = 0; mf < 2; ++mf)
#pragma unroll
        for (int nt = 0; nt < 4; ++nt)
#pragma unroll
            for (int r = 0; r < 4; ++r) {
                int n = n0 + wave * 32 + mf * 16 + quad * 4 + r;
                if (n < N_NODES) ft2b[(size_t)n * D2 + nt * 16 + mr] = f2bf(acc[mf][nt][r]);
            }
    float al2v[4], ar2v[4];
#pragma unroll
    for (int nt = 0; nt < 4; ++nt) { al2v[nt] = al2[nt * 16 + mr]; ar2v[nt] = ar2[nt * 16 + mr]; }
#pragma unroll
    for (int mf = 0; mf < 2; ++mf)
#pragma unroll
        for (int r = 0; r < 4; ++r) {
            int n = n0 + wave * 32 + mf * 16 + quad * 4 + r;
            float pl = 0.f, pr = 0.f;
#pragma unroll
            for (int nt = 0; nt < 4; ++nt) {
                float v = acc[mf][nt][r];
                pl = fmaf(v, al2v[nt], pl);
                pr = fmaf(v, ar2v[nt], pr);
            }
#pragma unroll
            for (int off = 1; off < 16; off <<= 1) {
                pl += __shfl_xor(pl, off, 64);
                pr += __shfl_xor(pr, off, 64);
            }
            if (mr == 0 && n < N_NODES) { el2[n] = pl; er2[n] = pr; }
        }
}

// ---------------- layer1 aggregation: half-wave per edge, 16 edges/wave in flight ------
__global__ __launch_bounds__(256) void k_agg2(const u16* __restrict__ ft2b,
                                              const float* __restrict__ el2,
                                              const float* __restrict__ er2,
                                              const int* __restrict__ row_start,
                                              const int* __restrict__ csr_src,
                                              float* __restrict__ out2) {
    int lane = threadIdx.x & 63;
    int n = blockIdx.x * 4 + (threadIdx.x >> 6);
    if (n >= N_NODES) return;
    int half = lane >> 5;
    int c = (lane & 31) * 2;            // channel pair
    float ern = er2[n];
    int beg = row_start[n], end = row_start[n + 1];
    float a0 = 0.f, a1 = 0.f, sw = 0.f;
    const u32* ftp = (const u32*)ft2b;  // row = 32 u32
    for (int base = beg; base < end; base += 64) {
        int rem = end - base;
        int sv = csr_src[base + ((lane < rem) ? lane : 0)];
        int cnt = rem < 64 ? rem : 64;
        for (int j = 0; j < cnt; j += 16) {
            int s[8];
#pragma unroll
            for (int kk = 0; kk < 8; ++kk) {
                int idx = j + 2 * kk + half;
                int sl = (idx < cnt) ? idx : j;
                s[kk] = __shfl(sv, sl, 64);
            }
            float e[8];
#pragma unroll
            for (int kk = 0; kk < 8; ++kk) e[kk] = el2[s[kk]];
            u32 f[8];
#pragma unroll
            for (int kk = 0; kk < 8; ++kk) f[kk] = ftp[(size_t)s[kk] * 32 + (lane & 31)];
#pragma unroll
            for (int kk = 0; kk < 8; ++kk) {
                float w = ((j + 2 * kk + half) < cnt) ? __expf(lrelu(e[kk] + ern)) : 0.f;
                a0 = fmaf(w, bflo(f[kk]), a0);
                a1 = fmaf(w, bfhi(f[kk]), a1);
                sw += w;
            }
        }
    }
    a0 += __shfl_xor(a0, 32, 64);
    a1 += __shfl_xor(a1, 32, 64);
    sw += __shfl_xor(sw, 32, 64);
    if (half == 0) {
        float2 rr;
        rr.x = (sw > 0.f) ? a0 / sw : 0.f;
        rr.y = (sw > 0.f) ? a1 / sw : 0.f;
        *(float2*)(out2 + (size_t)n * D2 + c) = rr;
    }
}

extern "C" void kernel_launch(void* const* d_in, const int* in_sizes, int n_in,
                              void* d_out, int out_size, void* d_ws, size_t ws_size,
                              hipStream_t stream) {
    const float* feats = (const float*)d_in[0];
    const int* src = (const int*)d_in[1];
    const int* dst = (const int*)d_in[2];
    const float* W1 = (const float*)d_in[3];
    const float* al1 = (const float*)d_in[4];
    const float* ar1 = (const float*)d_in[5];
    const float* W2 = (const float*)d_in[6];
    const float* al2 = (const float*)d_in[7];
    const float* ar2 = (const float*)d_in[8];

    float* out0 = (float*)d_out;                       // feats copy [N,512]
    float* out1 = out0 + (size_t)N_NODES * D_IN;       // h1 [N,128]
    float* out2 = out1 + (size_t)N_NODES * C1;         // h  [N,64]

    char* ws = (char*)d_ws;
    size_t off = 0;
    auto alloc = [&](size_t bytes) -> void* {
        void* p = ws + off;
        off = (off + bytes + 255) & ~(size_t)255;
        return p;
    };
    u16* ft1b = (u16*)alloc((size_t)N_NODES * C1 * 2);
    u16* h1b = (u16*)alloc((size_t)N_NODES * C1 * 2);
    u16* ft2b = (u16*)alloc((size_t)N_NODES * D2 * 2);
    float* eler1 = (float*)alloc((size_t)N_NODES * 16 * 4);   // [n][16]: el[0..7], er[0..7]
    float* el2 = (float*)alloc((size_t)N_NODES * 4);
    float* er2 = (float*)alloc((size_t)N_NODES * 4);
    int* cnt = (int*)alloc((size_t)N_NODES * 4);
    int* row_start = (int*)alloc((size_t)(N_NODES + 1) * 4);
    int* cursor = (int*)alloc((size_t)N_NODES * 4);
    int* csr_src = (int*)alloc((size_t)N_EDGES * 4);
    int* partials = (int*)alloc((size_t)NB_SCAN * 4);
    int* offsets = (int*)alloc((size_t)NB_SCAN * 4);

    // K0: zero the histogram
    hipMemsetAsync(cnt, 0, (size_t)N_NODES * 4, stream);

    // K1: gemm1 (layer0 transform + out0 copy + fused el1/er1) ∥ dst histogram
    k_gemm1_hist<<<G1 + NB_HIST, 256, 0, stream>>>(feats, W1, al1, ar1, ft1b, out0, eler1,
                                                   dst, cnt);

    // CSR build (scan x3 + scatter, small chained kernels)
    k_scan_partials<<<NB_SCAN, 256, 0, stream>>>(cnt, partials);
    k_scan_offsets<<<1, 128, 0, stream>>>(partials, offsets, row_start);
    k_scan_final<<<NB_SCAN, 256, 0, stream>>>(cnt, offsets, row_start, cursor);
    k_scatter<<<(N_EDGES + 255) / 256, 256, 0, stream>>>(src, dst, cursor, csr_src);

    // layer 0 aggregation
    k_agg1<<<(N_NODES + 3) / 4, 256, 0, stream>>>(ft1b, eler1, row_start, csr_src, out1, (u32*)h1b);

    // layer 1
    k_gemm2<<<(N_NODES + 127) / 128, 256, 0, stream>>>(h1b, W2, al2, ar2, ft2b, el2, er2);
    k_agg2<<<(N_NODES + 3) / 4, 256, 0, stream>>>(ft2b, el2, er2, row_start, csr_src, out2);
}